// Round 19
// baseline (55.193 us; speedup 1.0000x reference)
//
#include <hip/hip_runtime.h>

#define DIMV 16
#define NSTEP 4095      // 4096 - 1 increments
#define NC 64           // chunks
#define TSTEP 64        // chunk length
#define SIG13 4368      // 16 + 256 + 4096
#define L4 65536        // 16^4

// 16-wide register vector as explicit float4s — never runtime-indexed (rule #20).
struct V16 { float4 a, b, c, d; };

#define EACH(OP) OP(a,x) OP(a,y) OP(a,z) OP(a,w) OP(b,x) OP(b,y) OP(b,z) OP(b,w) \
                 OP(c,x) OP(c,y) OP(c,z) OP(c,w) OP(d,x) OP(d,y) OP(d,z) OP(d,w)

__device__ inline V16 ldv16(const float* p) {
    const float4* q = reinterpret_cast<const float4*>(p);
    V16 v; v.a = q[0]; v.b = q[1]; v.c = q[2]; v.d = q[3]; return v;
}
__device__ inline void stv16(float* p, const V16& v) {
    float4* q = reinterpret_cast<float4*>(p);
    q[0] = v.a; q[1] = v.b; q[2] = v.c; q[3] = v.d;
}
__device__ inline V16 zerov16() {
    V16 v; v.a = v.b = v.c = v.d = make_float4(0.f, 0.f, 0.f, 0.f); return v;
}

// ===== K1: chunk-LOCAL level-4 scan (from zero; no prefix dependency) =====
// block (cb, h): chunk cb, j-pair (2h, 2h+1). Stages the x-chunk into LDS once,
// computes dx in registers, runs the 64-step local recurrence. h==0 blocks also
// track the full local A3 and write the levels-1..3 chunk signature.
template <bool ATOMIC>
__global__ __launch_bounds__(256, 1) void k_local4(const float* __restrict__ x,
                                                   float* __restrict__ chunk_sig,
                                                   float* __restrict__ dst) {
    __shared__ float sx[(TSTEP + 1) * DIMV];   // 4.16 KB
    const int cb = blockIdx.x;   // 0..NC-1
    const int h = blockIdx.y;    // 0..7 : j-pair
    const int t = threadIdx.x;
    const int ia = t >> 4, ib = t & 15;

    const int s0 = cb * TSTEP;
    const int s1 = (s0 + TSTEP < NSTEP) ? (s0 + TSTEP) : NSTEP;
    const int nrow = s1 - s0;                  // 64 (63 for last chunk)

    // stage x rows s0 .. s0+nrow (nrow+1 rows), coalesced
    {
        const float4* src = reinterpret_cast<const float4*>(x + (size_t)s0 * DIMV);
        float4* sd4 = reinterpret_cast<float4*>(sx);
        const int nslot = (nrow + 1) * (DIMV / 4);   // <= 260
        if (t < nslot) sd4[t] = src[t];
        int slot2 = t + 256;
        if (slot2 < nslot) sd4[slot2] = src[slot2];
    }
    __syncthreads();

    float A1a = 0.f, A2 = 0.f;
    float2 A3p = make_float2(0.f, 0.f);
    V16 A3f = zerov16();                       // full level-3 (used when h==0)
    V16 ac0 = zerov16(), ac1 = zerov16();

    V16 xprev = ldv16(sx);
    float xpa = sx[ia], xpb = sx[ib];
    float2 xpj = *reinterpret_cast<const float2*>(sx + 2 * h);

    for (int si = 0; si < nrow; ++si) {
        const float* nr = sx + (si + 1) * DIMV;
        V16 xc = ldv16(nr);                    // wave-uniform -> LDS broadcast
        float xca = nr[ia];
        float xcb = nr[ib];
        float2 xcj = *reinterpret_cast<const float2*>(nr + 2 * h);

        V16 dxv;
#define SB(Q,C) dxv.Q.C = xc.Q.C - xprev.Q.C;
        EACH(SB)
#undef SB
        float dxa = xca - xpa;
        float dxb = xcb - xpb;
        float2 dj = make_float2(xcj.x - xpj.x, xcj.y - xpj.y);

        float U2 = fmaf(dxb, fmaf(dxa, 1.f/24.f, A1a * (1.f/6.f)), 0.5f * A2);
        float V2 = fmaf(dxb, fmaf(dxa, 1.f/6.f, A1a * 0.5f), A2);
        float h2 = fmaf(dxa, 0.5f, A1a);
        float u30 = fmaf(dj.x, U2, A3p.x);
        float u31 = fmaf(dj.y, U2, A3p.y);
#define AC(Q,C) { ac0.Q.C = fmaf(u30, dxv.Q.C, ac0.Q.C); \
                  ac1.Q.C = fmaf(u31, dxv.Q.C, ac1.Q.C); }
        EACH(AC)
#undef AC
        A3p.x = fmaf(dj.x, V2, A3p.x);
        A3p.y = fmaf(dj.y, V2, A3p.y);
        if (h == 0) {                           // full A3 for chunk_sig
#define CS(Q,C) A3f.Q.C = fmaf(dxv.Q.C, V2, A3f.Q.C);
            EACH(CS)
#undef CS
        }
        A2 = fmaf(dxb, h2, A2);
        A1a += dxa;

        xprev = xc; xpa = xca; xpb = xcb; xpj = xcj;
    }

    if (ATOMIC) {
        float* o = dst + t * 256 + (h * 2) * 16;
#define STA(Q,C,K) atomicAdd(o + (K), ac0.Q.C); atomicAdd(o + 16 + (K), ac1.Q.C);
        STA(a,x,0) STA(a,y,1) STA(a,z,2) STA(a,w,3)
        STA(b,x,4) STA(b,y,5) STA(b,z,6) STA(b,w,7)
        STA(c,x,8) STA(c,y,9) STA(c,z,10) STA(c,w,11)
        STA(d,x,12) STA(d,y,13) STA(d,z,14) STA(d,w,15)
#undef STA
    } else {
        float* o = dst + (size_t)cb * L4 + t * 256 + (h * 2) * 16;
        stv16(o, ac0);
        stv16(o + 16, ac1);
    }

    if (h == 0) {
        float* o = chunk_sig + (size_t)cb * SIG13;
        if (ib == 0) o[ia] = A1a;
        o[16 + t] = A2;
        stv16(o + 272 + t * 16, A3f);
    }
}

// ===== K2: fused cascaded prefix (levels 1,2,3) — R12-proven, unchanged =====
__global__ __launch_bounds__(256, 1) void k_prefixB(const float* __restrict__ chunk_sig,
                                                    float* __restrict__ prefix_sig,
                                                    float* __restrict__ out13) {
    __shared__ float s1s[NC][16];
    __shared__ float p1s[NC][16];
    __shared__ float p2s[NC][16];
    const int a = blockIdx.x;
    const int t = threadIdx.x;

    for (int base = 0; base < NC; base += 16) {
        int c = base + (t >> 4);
        s1s[c][t & 15] = chunk_sig[(size_t)c * SIG13 + (t & 15)];
    }
    __syncthreads();
    if (t < 16) {
        float p = 0.f;
        for (int c = 0; c < NC; ++c) {
            p1s[c][t] = p;
            if (a == 0) prefix_sig[(size_t)c * SIG13 + t] = p;
            p += s1s[c][t];
        }
        if (a == 0) out13[t] = p;
    }
    __syncthreads();
    {
        const int aa = t >> 4, bb = t & 15;
        float pl0 = chunk_sig[0ul * SIG13 + 16 + t];
        float pl1 = chunk_sig[1ul * SIG13 + 16 + t];
        float pl2 = chunk_sig[2ul * SIG13 + 16 + t];
        float pl3 = chunk_sig[3ul * SIG13 + 16 + t];
        float pl4 = chunk_sig[4ul * SIG13 + 16 + t];
        float pl5 = chunk_sig[5ul * SIG13 + 16 + t];
        float pl6 = chunk_sig[6ul * SIG13 + 16 + t];
        float pl7 = chunk_sig[7ul * SIG13 + 16 + t];
        float p = 0.f;
        for (int cb2 = 0; cb2 < NC; cb2 += 8) {
#define STEP2(J) { int c = cb2 + J; \
            if (aa == a) p2s[c][bb] = p; \
            if (a == 0) prefix_sig[(size_t)c * SIG13 + 16 + t] = p; \
            p = fmaf(p1s[c][aa], s1s[c][bb], p + pl##J); \
            int cn = c + 8; \
            if (cn < NC) pl##J = chunk_sig[(size_t)cn * SIG13 + 16 + t]; }
            STEP2(0) STEP2(1) STEP2(2) STEP2(3) STEP2(4) STEP2(5) STEP2(6) STEP2(7)
#undef STEP2
        }
        if (a == 0) out13[16 + t] = p;
    }
    __syncthreads();
    {
        const int c3 = t & 15, k = t >> 4;
        const size_t off3 = 272 + (size_t)a * 256 + t;
#define LD3(J, C) \
        float l3_##J = chunk_sig[(size_t)(C) * SIG13 + off3]; \
        float l2_##J = chunk_sig[(size_t)(C) * SIG13 + 16 + t];
        LD3(0,0) LD3(1,1) LD3(2,2) LD3(3,3) LD3(4,4) LD3(5,5) LD3(6,6) LD3(7,7)
#undef LD3
        float p = 0.f;
        for (int cb2 = 0; cb2 < NC; cb2 += 8) {
#define STEP3(J) { int c = cb2 + J; \
            prefix_sig[(size_t)c * SIG13 + off3] = p; \
            p = p + l3_##J + fmaf(p1s[c][a], l2_##J, p2s[c][k] * s1s[c][c3]); \
            int cn = c + 8; \
            if (cn < NC) { \
                l3_##J = chunk_sig[(size_t)cn * SIG13 + off3]; \
                l2_##J = chunk_sig[(size_t)cn * SIG13 + 16 + t]; } }
            STEP3(0) STEP3(1) STEP3(2) STEP3(3) STEP3(4) STEP3(5) STEP3(6) STEP3(7)
#undef STEP3
        }
        out13[off3] = p;
    }
}

// ===== K3: combine = reduce(partials) + Chen corrections =====
// out4[e] = sum_c { part_c[e] + P1_c[a]*L3_c[b,j,d] + P2_c[a,b]*L2_c[j,d]
//                   + P3_c[a,b,j]*L1_c[d] },  e = a*4096+b*256+j*16+d.
template <bool HAVE_PART>
__global__ __launch_bounds__(256, 1) void k_combine(const float* __restrict__ partials,
                                                    const float* __restrict__ chunk_sig,
                                                    const float* __restrict__ prefix_sig,
                                                    float* __restrict__ out4) {
    const int e = blockIdx.x * 256 + threadIdx.x;  // 0..65535
    const int i_l3 = 272 + (e & 4095);
    const int i_l2 = 16 + (e & 255);
    const int i_l1 = e & 15;
    const int i_p1 = e >> 12;
    const int i_p2 = 16 + (e >> 8);
    const int i_p3 = 272 + (e >> 4);

    float s = 0.f;
#pragma unroll 4
    for (int c = 0; c < NC; ++c) {
        const float* B = chunk_sig + (size_t)c * SIG13;
        const float* P = prefix_sig + (size_t)c * SIG13;
        float corr = fmaf(P[i_p1], B[i_l3],
                     fmaf(P[i_p2], B[i_l2], P[i_p3] * B[i_l1]));
        if (HAVE_PART) s += partials[(size_t)c * L4 + e] + corr;
        else           s += corr;
    }
    if (HAVE_PART) out4[e] = s;
    else           out4[e] += s;   // local-L4 already atomically accumulated
}

extern "C" void kernel_launch(void* const* d_in, const int* in_sizes, int n_in,
                              void* d_out, int out_size, void* d_ws, size_t ws_size,
                              hipStream_t stream) {
    const float* x = (const float*)d_in[0];
    float* out = (float*)d_out;
    float* ws = (float*)d_ws;

    float* chunk_sig = ws;                               // NC * SIG13
    float* prefix_sig = chunk_sig + (size_t)NC * SIG13;  // NC * SIG13
    float* partials = prefix_sig + (size_t)NC * SIG13;   // NC * L4
    const size_t need_bytes =
        (2ull * NC * SIG13 + (size_t)NC * L4) * sizeof(float);

    if (ws_size >= need_bytes) {
        k_local4<false><<<dim3(NC, 8), dim3(256), 0, stream>>>(x, chunk_sig, partials);
        k_prefixB<<<dim3(16), dim3(256), 0, stream>>>(chunk_sig, prefix_sig, out);
        k_combine<true><<<dim3(256), dim3(256), 0, stream>>>(partials, chunk_sig,
                                                             prefix_sig, out + SIG13);
    } else {
        hipMemsetAsync(out + SIG13, 0, (size_t)L4 * sizeof(float), stream);
        k_local4<true><<<dim3(NC, 8), dim3(256), 0, stream>>>(x, chunk_sig, out + SIG13);
        k_prefixB<<<dim3(16), dim3(256), 0, stream>>>(chunk_sig, prefix_sig, out);
        k_combine<false><<<dim3(256), dim3(256), 0, stream>>>(nullptr, chunk_sig,
                                                              prefix_sig, out + SIG13);
    }
}